// Round 2
// baseline (1559.329 us; speedup 1.0000x reference)
//
#include <hip/hip_runtime.h>
#include <hip/hip_bf16.h>

__device__ __forceinline__ float softplusf(float x) {
    return fmaxf(x, 0.f) + log1pf(expf(-fabsf(x)));
}

// ---------------------------------------------------------------------------
// Kernel P: pre-transpose weights (run once per launch, 1 block).
// wst_lin[(cin*9+k)*32 + cout] = lin_w[cout*144 + cin*9 + k]         (4608)
// wst_node[((conv*16+cin)*9+k)*16 + cout] = {edge_w,node_w}[...]     (4608)
// ---------------------------------------------------------------------------
__global__ __launch_bounds__(256) void prep_kernel(
    const float* __restrict__ edge_w, const float* __restrict__ node_w,
    const float* __restrict__ lin_w,
    float* __restrict__ wst_lin, float* __restrict__ wst_node)
{
    const int t = threadIdx.x;
    for (int i = t; i < 4608; i += 256) {
        // dest layout [cin][k][cout32]
        int cout = i & 31;
        int r = i >> 5;          // cin*9 + k
        wst_lin[i] = lin_w[cout * 144 + r];
    }
    for (int i = t; i < 4608; i += 256) {
        // dest layout [conv][cin][k][cout16]
        int cout = i & 15;
        int r = i >> 4;          // conv*144 + cin*9 + k
        int conv = r / 144;
        int r2 = r - conv * 144; // cin*9+k
        wst_node[i] = (conv == 0 ? edge_w : node_w)[cout * 144 + r2];
    }
}

// ---------------------------------------------------------------------------
// Kernel A: node-level convs. zc = conv3x3(atom, edge_w), nc = conv3x3(atom, node_w)
// One block per node, 256 threads = 16 cout x 2 conv x 8 rows.
// ---------------------------------------------------------------------------
__global__ __launch_bounds__(256) void node_conv_kernel(
    const float* __restrict__ atom, const float* __restrict__ wst_node,
    float* __restrict__ zc, float* __restrict__ nc)
{
    __shared__ float xs[16][10][12];      // zero-padded tile, 12-word pitch (16B-aligned rows)
    __shared__ float ws[2][16][9][16];    // [conv][cin][k][cout]
    const int n = blockIdx.x;
    const int t = threadIdx.x;

    float* wsf = &ws[0][0][0][0];
    for (int i = t; i < 4608; i += 256) wsf[i] = wst_node[i];   // coalesced + conflict-free
    float* xsf = &xs[0][0][0];
    for (int i = t; i < 16 * 10 * 12; i += 256) xsf[i] = 0.f;
    __syncthreads();
    for (int i = t; i < 1024; i += 256) {
        int c = i >> 6, pix = i & 63;
        xs[c][(pix >> 3) + 1][(pix & 7) + 1] = atom[(size_t)n * 1024 + i];
    }
    __syncthreads();

    const int cout = t & 15;
    const int conv = (t >> 4) & 1;
    const int row  = t >> 5;   // 0..7
    float acc[8] = {0, 0, 0, 0, 0, 0, 0, 0};
    for (int cin = 0; cin < 16; ++cin) {
        float w[9];
        #pragma unroll
        for (int j = 0; j < 9; ++j) w[j] = ws[conv][cin][j][cout];
        float r[3][10];
        #pragma unroll
        for (int k = 0; k < 3; ++k)
            #pragma unroll
            for (int c2 = 0; c2 < 10; ++c2) r[k][c2] = xs[cin][row + k][c2];
        #pragma unroll
        for (int x = 0; x < 8; ++x) {
            float a = acc[x];
            a += w[0] * r[0][x] + w[1] * r[0][x + 1] + w[2] * r[0][x + 2];
            a += w[3] * r[1][x] + w[4] * r[1][x + 1] + w[5] * r[1][x + 2];
            a += w[6] * r[2][x] + w[7] * r[2][x + 1] + w[8] * r[2][x + 2];
            acc[x] = a;
        }
    }
    float* dst = (conv == 0) ? zc : nc;
    #pragma unroll
    for (int x = 0; x < 8; ++x)
        dst[(size_t)n * 1024 + cout * 64 + row * 8 + x] = acc[x];
}

// ---------------------------------------------------------------------------
// Kernel B: per-edge. z = elu(nc[src]*zc[tgt]); t = conv3x3(z, lin_w)+b;
// msg = sigmoid(t[:16])*softplus(t[16:]); atomicAdd into acc[src] (= d_out).
// One block per edge, 256 threads = 32 cout x 8 rows.
// ---------------------------------------------------------------------------
__global__ __launch_bounds__(256) void edge_kernel(
    const float* __restrict__ zc, const float* __restrict__ nc,
    const int* __restrict__ esrc, const int* __restrict__ etgt,
    const float* __restrict__ wst_lin, const float* __restrict__ lin_b,
    float* __restrict__ acc)
{
    __shared__ float zs[16][10][12];      // zero-padded gated tile
    __shared__ float ws[16][9][32];       // [cin][k][cout32]
    __shared__ float bs[32];
    const int e = blockIdx.x;
    const int t = threadIdx.x;
    const int s = esrc[e];
    const int g = etgt[e];

    float* wsf = &ws[0][0][0];
    for (int i = t; i < 4608; i += 256) wsf[i] = wst_lin[i];   // coalesced + conflict-free
    if (t < 32) bs[t] = lin_b[t];
    float* zsf = &zs[0][0][0];
    for (int i = t; i < 16 * 10 * 12; i += 256) zsf[i] = 0.f;
    __syncthreads();
    for (int i = t; i < 1024; i += 256) {
        float z = nc[(size_t)s * 1024 + i] * zc[(size_t)g * 1024 + i];
        z = (z > 0.f) ? z : expm1f(z);   // elu, alpha=1
        int c = i >> 6, pix = i & 63;
        zs[c][(pix >> 3) + 1][(pix & 7) + 1] = z;
    }
    __syncthreads();

    const int cout = t & 31;
    const int row  = t >> 5;   // 0..7
    float acc8[8] = {0, 0, 0, 0, 0, 0, 0, 0};
    for (int cin = 0; cin < 16; ++cin) {
        float w[9];
        #pragma unroll
        for (int j = 0; j < 9; ++j) w[j] = ws[cin][j][cout];
        float r[3][10];
        #pragma unroll
        for (int k = 0; k < 3; ++k)
            #pragma unroll
            for (int c2 = 0; c2 < 10; ++c2) r[k][c2] = zs[cin][row + k][c2];
        #pragma unroll
        for (int x = 0; x < 8; ++x) {
            float a = acc8[x];
            a += w[0] * r[0][x] + w[1] * r[0][x + 1] + w[2] * r[0][x + 2];
            a += w[3] * r[1][x] + w[4] * r[1][x + 1] + w[5] * r[1][x + 2];
            a += w[6] * r[2][x] + w[7] * r[2][x + 1] + w[8] * r[2][x + 2];
            acc8[x] = a;
        }
    }
    const float b = bs[cout];
    float tv[8];
    #pragma unroll
    for (int x = 0; x < 8; ++x) tv[x] = acc8[x] + b;

    // pair (cout, cout+16): lane ^ 16 swaps halves within the wave
    #pragma unroll
    for (int x = 0; x < 8; ++x) {
        float core = __shfl_xor(tv[x], 16, 64);
        if (cout < 16) {
            float sig = 1.f / (1.f + expf(-tv[x]));
            float msg = sig * softplusf(core);
            atomicAdd(&acc[(size_t)s * 1024 + cout * 64 + row * 8 + x], msg);
        }
    }
}

// ---------------------------------------------------------------------------
// Kernel C: epilogue, in place on d_out (holds sum of msgs).
// out = softplus(a + (a + acc)*gamma/sqrt(1+eps) + beta)
// ---------------------------------------------------------------------------
__global__ __launch_bounds__(256) void final_kernel(
    const float4* __restrict__ atom, float4* __restrict__ out,
    const float* __restrict__ gamma, const float* __restrict__ beta, int total4)
{
    int i = blockIdx.x * 256 + threadIdx.x;
    if (i >= total4) return;
    int c = ((i * 4) >> 6) & 15;   // 4 consecutive floats share the channel
    const float scale = gamma[c] * (1.f / sqrtf(1.f + 1e-5f));
    const float bet = beta[c];
    float4 a = atom[i];
    float4 s = out[i];
    float4 r;
    r.x = softplusf(a.x + (a.x + s.x) * scale + bet);
    r.y = softplusf(a.y + (a.y + s.y) * scale + bet);
    r.z = softplusf(a.z + (a.z + s.z) * scale + bet);
    r.w = softplusf(a.w + (a.w + s.w) * scale + bet);
    out[i] = r;
}

extern "C" void kernel_launch(void* const* d_in, const int* in_sizes, int n_in,
                              void* d_out, int out_size, void* d_ws, size_t ws_size,
                              hipStream_t stream) {
    const float* atom   = (const float*)d_in[0];
    const int*   esrc   = (const int*)d_in[1];
    const int*   etgt   = (const int*)d_in[2];
    const float* edge_w = (const float*)d_in[3];
    const float* node_w = (const float*)d_in[4];
    const float* lin_w  = (const float*)d_in[5];
    const float* lin_b  = (const float*)d_in[6];
    const float* gamma  = (const float*)d_in[7];
    const float* beta   = (const float*)d_in[8];
    float* out = (float*)d_out;

    const int total = in_sizes[0];      // N*16*8*8 = 8,192,000
    const int N = total / 1024;         // 8000
    const int E = in_sizes[1];          // 48000

    char* wsb = (char*)d_ws;
    float* zc       = (float*)wsb;                                  // total fp32
    float* nc       = (float*)(wsb + (size_t)total * 4);            // total fp32
    float* wst_lin  = (float*)(wsb + (size_t)total * 8);            // 4608 fp32
    float* wst_node = wst_lin + 4608;                               // 4608 fp32

    hipMemsetAsync(out, 0, (size_t)total * 4, stream);   // msg accumulator
    prep_kernel<<<1, 256, 0, stream>>>(edge_w, node_w, lin_w, wst_lin, wst_node);
    node_conv_kernel<<<N, 256, 0, stream>>>(atom, wst_node, zc, nc);
    edge_kernel<<<E, 256, 0, stream>>>(zc, nc, esrc, etgt, wst_lin, lin_b, out);
    final_kernel<<<(total / 4 + 255) / 256, 256, 0, stream>>>(
        (const float4*)atom, (float4*)out, gamma, beta, total / 4);
}

// Round 3
// 1536.753 us; speedup vs baseline: 1.0147x; 1.0147x over previous
//
#include <hip/hip_runtime.h>

__device__ __forceinline__ float softplusf(float x) {
    return fmaxf(x, 0.f) + log1pf(expf(-fabsf(x)));
}

// ---------------------------------------------------------------------------
// Kernel P: pre-transpose weights into block-staging-ready layouts.
// wst_lin [(cin*9+j)*32 + c*2 + h]              = lin_w[(c+16h)*144 + cin*9+j]   (c<16,h<2)
// wst_node[((conv*16+cin)*9+j)*16 + c*2 + h]    = {edge,node}_w[(c+8h)*144+cin*9+j] (c<8)
// ---------------------------------------------------------------------------
__global__ __launch_bounds__(256) void prep_kernel(
    const float* __restrict__ edge_w, const float* __restrict__ node_w,
    const float* __restrict__ lin_w,
    float* __restrict__ wst_lin, float* __restrict__ wst_node)
{
    const int t = threadIdx.x;
    for (int i = t; i < 4608; i += 256) {
        int h = i & 1;
        int c = (i >> 1) & 15;
        int r = i >> 5;                    // cin*9 + j
        wst_lin[i] = lin_w[(c + 16 * h) * 144 + r];
    }
    for (int i = t; i < 4608; i += 256) {
        int h = i & 1;
        int c = (i >> 1) & 7;
        int r = i >> 4;                    // conv*144 + cin*9 + j
        int conv = r / 144;
        int r2 = r - conv * 144;
        wst_node[i] = (conv == 0 ? edge_w : node_w)[(c + 8 * h) * 144 + r2];
    }
}

// ---------------------------------------------------------------------------
// Kernel A: node convs, 2 nodes/block. thread = (node, conv, cout-pair c/c+8, row)
// ---------------------------------------------------------------------------
__global__ __launch_bounds__(256, 4) void node_conv_kernel(
    const float* __restrict__ atom, const float* __restrict__ wst_node,
    float* __restrict__ zc, float* __restrict__ nc, int N)
{
    __shared__ float xs[2][16][10][12];      // 15360 B, 12-word pitch (16B-aligned rows)
    __shared__ float ws[2][16][9][8][2];     // [conv][cin][j][c][h] 18432 B
    const int t = threadIdx.x;
    const int n0 = blockIdx.x * 2;
    const bool dup = (n0 + 1 >= N);
    const int n1 = dup ? n0 : n0 + 1;

    float* wsf = &ws[0][0][0][0][0];
    for (int i = t; i < 4608; i += 256) wsf[i] = wst_node[i];   // straight copy
    float* xsf = &xs[0][0][0][0];
    for (int i = t; i < 2 * 16 * 10 * 12; i += 256) xsf[i] = 0.f;
    __syncthreads();
    for (int i = t; i < 2048; i += 256) {
        int nd = i >> 10, j = i & 1023;
        int ch = j >> 6, pix = j & 63;
        xs[nd][ch][(pix >> 3) + 1][(pix & 7) + 1] =
            atom[(size_t)(nd ? n1 : n0) * 1024 + j];
    }
    __syncthreads();

    const int nd   = t >> 7;
    const int conv = (t >> 6) & 1;
    const int c    = (t >> 3) & 7;
    const int row  = t & 7;

    float tf[8] = {0,0,0,0,0,0,0,0};
    float tc[8] = {0,0,0,0,0,0,0,0};
    const float* zrow = &xs[nd][0][row][0];
    const float2* wbase = (const float2*)&ws[conv][0][0][c][0];  // +(cin*9+j)*8

    #pragma unroll 4
    for (int cin = 0; cin < 16; ++cin) {
        float2 w[9];
        #pragma unroll
        for (int j = 0; j < 9; ++j) w[j] = wbase[(cin * 9 + j) * 8];
        float r[3][12];
        #pragma unroll
        for (int k = 0; k < 3; ++k) {
            const float4* rp = (const float4*)(zrow + cin * 120 + k * 12);
            float4 a = rp[0], b = rp[1], d = rp[2];
            r[k][0]=a.x; r[k][1]=a.y; r[k][2]=a.z; r[k][3]=a.w;
            r[k][4]=b.x; r[k][5]=b.y; r[k][6]=b.z; r[k][7]=b.w;
            r[k][8]=d.x; r[k][9]=d.y; r[k][10]=d.z; r[k][11]=d.w;
        }
        #pragma unroll
        for (int x = 0; x < 8; ++x) {
            float sf = tf[x], sc = tc[x];
            #pragma unroll
            for (int k = 0; k < 3; ++k) {
                sf += w[k*3+0].x * r[k][x] + w[k*3+1].x * r[k][x+1] + w[k*3+2].x * r[k][x+2];
                sc += w[k*3+0].y * r[k][x] + w[k*3+1].y * r[k][x+1] + w[k*3+2].y * r[k][x+2];
            }
            tf[x] = sf; tc[x] = sc;
        }
    }
    if (nd == 1 && dup) return;
    const size_t base = (size_t)(nd ? n1 : n0) * 1024;
    float* dst = conv ? nc : zc;
    #pragma unroll
    for (int x = 0; x < 8; ++x) {
        dst[base + c * 64 + row * 8 + x]       = tf[x];
        dst[base + (c + 8) * 64 + row * 8 + x] = tc[x];
    }
}

// ---------------------------------------------------------------------------
// Kernel B: edge conv, 2 edges/block. thread = (edge, cout-pair c/c+16, row)
// z = elu(nc[src]*zc[tgt]); t = conv3x3(z, lin_w)+b;
// msg = sigmoid(t[:16])*softplus(t[16:]); atomicAdd into out[src].
// ---------------------------------------------------------------------------
__global__ __launch_bounds__(256, 4) void edge_kernel(
    const float* __restrict__ zc, const float* __restrict__ nc,
    const int* __restrict__ esrc, const int* __restrict__ etgt,
    const float* __restrict__ wst_lin, const float* __restrict__ lin_b,
    float* __restrict__ acc, int E)
{
    __shared__ float zs[2][16][10][12];      // 15360 B
    __shared__ float ws[16][9][16][2];       // [cin][j][c][h] 18432 B
    __shared__ float bs[32];
    const int t = threadIdx.x;
    const int e0 = blockIdx.x * 2;
    const bool dup = (e0 + 1 >= E);
    const int e1 = dup ? e0 : e0 + 1;
    const int s0 = esrc[e0], g0 = etgt[e0];
    const int s1 = esrc[e1], g1 = etgt[e1];

    float* wsf = &ws[0][0][0][0];
    for (int i = t; i < 4608; i += 256) wsf[i] = wst_lin[i];    // straight copy
    if (t < 32) bs[t] = lin_b[t];
    float* zsf = &zs[0][0][0][0];
    for (int i = t; i < 2 * 16 * 10 * 12; i += 256) zsf[i] = 0.f;
    __syncthreads();
    for (int i = t; i < 2048; i += 256) {
        int nd = i >> 10, j = i & 1023;
        int s = nd ? s1 : s0, g = nd ? g1 : g0;
        float z = nc[(size_t)s * 1024 + j] * zc[(size_t)g * 1024 + j];
        z = (z > 0.f) ? z : expm1f(z);       // elu, alpha=1
        int ch = j >> 6, pix = j & 63;
        zs[nd][ch][(pix >> 3) + 1][(pix & 7) + 1] = z;
    }
    __syncthreads();

    const int nd  = t >> 7;                  // edge within block
    const int c   = (t >> 3) & 15;
    const int row = t & 7;

    float tf[8] = {0,0,0,0,0,0,0,0};
    float tc[8] = {0,0,0,0,0,0,0,0};
    const float* zrow = &zs[nd][0][row][0];
    const float2* wbase = (const float2*)&ws[0][0][c][0];        // +(cin*9+j)*16

    #pragma unroll 4
    for (int cin = 0; cin < 16; ++cin) {
        float2 w[9];
        #pragma unroll
        for (int j = 0; j < 9; ++j) w[j] = wbase[(cin * 9 + j) * 16];
        float r[3][12];
        #pragma unroll
        for (int k = 0; k < 3; ++k) {
            const float4* rp = (const float4*)(zrow + cin * 120 + k * 12);
            float4 a = rp[0], b = rp[1], d = rp[2];
            r[k][0]=a.x; r[k][1]=a.y; r[k][2]=a.z; r[k][3]=a.w;
            r[k][4]=b.x; r[k][5]=b.y; r[k][6]=b.z; r[k][7]=b.w;
            r[k][8]=d.x; r[k][9]=d.y; r[k][10]=d.z; r[k][11]=d.w;
        }
        #pragma unroll
        for (int x = 0; x < 8; ++x) {
            float sf = tf[x], sc = tc[x];
            #pragma unroll
            for (int k = 0; k < 3; ++k) {
                sf += w[k*3+0].x * r[k][x] + w[k*3+1].x * r[k][x+1] + w[k*3+2].x * r[k][x+2];
                sc += w[k*3+0].y * r[k][x] + w[k*3+1].y * r[k][x+1] + w[k*3+2].y * r[k][x+2];
            }
            tf[x] = sf; tc[x] = sc;
        }
    }
    if (nd == 1 && dup) return;
    const int s = nd ? s1 : s0;
    const float bf = bs[c], bc = bs[c + 16];
    #pragma unroll
    for (int x = 0; x < 8; ++x) {
        float f = tf[x] + bf;
        float co = tc[x] + bc;
        float sig = 1.f / (1.f + expf(-f));
        float msg = sig * softplusf(co);
        atomicAdd(&acc[(size_t)s * 1024 + c * 64 + row * 8 + x], msg);
    }
}

// ---------------------------------------------------------------------------
// Kernel C: epilogue, in place on d_out (holds sum of msgs).
// out = softplus(a + (a + acc)*gamma/sqrt(1+eps) + beta)
// ---------------------------------------------------------------------------
__global__ __launch_bounds__(256) void final_kernel(
    const float4* __restrict__ atom, float4* __restrict__ out,
    const float* __restrict__ gamma, const float* __restrict__ beta, int total4)
{
    int i = blockIdx.x * 256 + threadIdx.x;
    if (i >= total4) return;
    int c = ((i * 4) >> 6) & 15;
    const float scale = gamma[c] * (1.f / sqrtf(1.f + 1e-5f));
    const float bet = beta[c];
    float4 a = atom[i];
    float4 s = out[i];
    float4 r;
    r.x = softplusf(a.x + (a.x + s.x) * scale + bet);
    r.y = softplusf(a.y + (a.y + s.y) * scale + bet);
    r.z = softplusf(a.z + (a.z + s.z) * scale + bet);
    r.w = softplusf(a.w + (a.w + s.w) * scale + bet);
    out[i] = r;
}

extern "C" void kernel_launch(void* const* d_in, const int* in_sizes, int n_in,
                              void* d_out, int out_size, void* d_ws, size_t ws_size,
                              hipStream_t stream) {
    const float* atom   = (const float*)d_in[0];
    const int*   esrc   = (const int*)d_in[1];
    const int*   etgt   = (const int*)d_in[2];
    const float* edge_w = (const float*)d_in[3];
    const float* node_w = (const float*)d_in[4];
    const float* lin_w  = (const float*)d_in[5];
    const float* lin_b  = (const float*)d_in[6];
    const float* gamma  = (const float*)d_in[7];
    const float* beta   = (const float*)d_in[8];
    float* out = (float*)d_out;

    const int total = in_sizes[0];      // N*16*8*8
    const int N = total / 1024;         // 8000
    const int E = in_sizes[1];          // 48000

    char* wsb = (char*)d_ws;
    float* zcb      = (float*)wsb;                                  // total fp32
    float* ncb      = (float*)(wsb + (size_t)total * 4);            // total fp32
    float* wst_lin  = (float*)(wsb + (size_t)total * 8);            // 4608 fp32
    float* wst_node = wst_lin + 4608;                               // 4608 fp32

    hipMemsetAsync(out, 0, (size_t)total * 4, stream);   // msg accumulator
    prep_kernel<<<1, 256, 0, stream>>>(edge_w, node_w, lin_w, wst_lin, wst_node);
    node_conv_kernel<<<(N + 1) / 2, 256, 0, stream>>>(atom, wst_node, zcb, ncb, N);
    edge_kernel<<<(E + 1) / 2, 256, 0, stream>>>(zcb, ncb, esrc, etgt, wst_lin, lin_b, out, E);
    final_kernel<<<(total / 4 + 255) / 256, 256, 0, stream>>>(
        (const float4*)atom, (float4*)out, gamma, beta, total / 4);
}

// Round 4
// 808.171 us; speedup vs baseline: 1.9295x; 1.9015x over previous
//
#include <hip/hip_runtime.h>

__device__ __forceinline__ float softplusf(float x) {
    return fmaxf(x, 0.f) + log1pf(expf(-fabsf(x)));
}

// ---------------------------------------------------------------------------
// Kernel P: pre-transpose weights into block-staging-ready layouts.
// wst_lin [(cin*9+j)*32 + c*2 + h]           = lin_w[(c+16h)*144 + cin*9+j]   (c<16,h<2)
// wst_node[((conv*16+cin)*9+j)*16 + c*2 + h] = {edge,node}_w[(c+8h)*144+cin*9+j] (c<8)
// ---------------------------------------------------------------------------
__global__ __launch_bounds__(256) void prep_kernel(
    const float* __restrict__ edge_w, const float* __restrict__ node_w,
    const float* __restrict__ lin_w,
    float* __restrict__ wst_lin, float* __restrict__ wst_node)
{
    const int t = threadIdx.x;
    for (int i = t; i < 4608; i += 256) {
        int h = i & 1;
        int c = (i >> 1) & 15;
        int r = i >> 5;                    // cin*9 + j
        wst_lin[i] = lin_w[(c + 16 * h) * 144 + r];
    }
    for (int i = t; i < 4608; i += 256) {
        int h = i & 1;
        int c = (i >> 1) & 7;
        int r = i >> 4;                    // conv*144 + cin*9 + j
        int conv = r / 144;
        int r2 = r - conv * 144;
        wst_node[i] = (conv == 0 ? edge_w : node_w)[(c + 8 * h) * 144 + r2];
    }
}

// ---------------------------------------------------------------------------
// Binning: histogram -> exclusive scan -> scatter (edge targets bucketed by src)
// ---------------------------------------------------------------------------
__global__ __launch_bounds__(256) void hist_kernel(
    const int* __restrict__ esrc, int* __restrict__ counts, int E)
{
    int i = blockIdx.x * 256 + threadIdx.x;
    if (i < E) atomicAdd(&counts[esrc[i]], 1);
}

__global__ __launch_bounds__(256) void scan_kernel(
    const int* __restrict__ counts, int* __restrict__ offsets, int N)
{
    __shared__ int part[256];
    const int t = threadIdx.x;
    const int chunk = (N + 255) / 256;
    const int base = t * chunk;
    int s = 0;
    for (int i = 0; i < chunk; ++i) {
        int idx = base + i;
        if (idx < N) s += counts[idx];
    }
    part[t] = s;
    __syncthreads();
    for (int d = 1; d < 256; d <<= 1) {
        int v = (t >= d) ? part[t - d] : 0;
        __syncthreads();
        part[t] += v;
        __syncthreads();
    }
    int excl = (t == 0) ? 0 : part[t - 1];
    for (int i = 0; i < chunk; ++i) {
        int idx = base + i;
        if (idx < N) { offsets[idx] = excl; excl += counts[idx]; }
    }
    if (t == 255) offsets[N] = excl;
}

__global__ __launch_bounds__(256) void scatter_kernel(
    const int* __restrict__ esrc, const int* __restrict__ etgt,
    const int* __restrict__ offsets, int* __restrict__ cursor,
    int* __restrict__ bucket_tgt, int E)
{
    int i = blockIdx.x * 256 + threadIdx.x;
    if (i < E) {
        int s = esrc[i];
        int pos = atomicAdd(&cursor[s], 1);
        bucket_tgt[offsets[s] + pos] = etgt[i];
    }
}

// ---------------------------------------------------------------------------
// Kernel A: node convs, 2 nodes/block. thread = (node, conv, cout-pair c/c+8, row)
// ---------------------------------------------------------------------------
__global__ __launch_bounds__(256, 4) void node_conv_kernel(
    const float* __restrict__ atom, const float* __restrict__ wst_node,
    float* __restrict__ zc, float* __restrict__ nc, int N)
{
    __shared__ float xs[2][16][10][12];      // 12-word pitch (16B-aligned rows)
    __shared__ float ws[2][16][9][8][2];     // [conv][cin][j][c][h]
    const int t = threadIdx.x;
    const int n0 = blockIdx.x * 2;
    const bool dup = (n0 + 1 >= N);
    const int n1 = dup ? n0 : n0 + 1;

    float* wsf = &ws[0][0][0][0][0];
    for (int i = t; i < 4608; i += 256) wsf[i] = wst_node[i];
    float* xsf = &xs[0][0][0][0];
    for (int i = t; i < 2 * 16 * 10 * 12; i += 256) xsf[i] = 0.f;
    __syncthreads();
    for (int i = t; i < 2048; i += 256) {
        int nd = i >> 10, j = i & 1023;
        int ch = j >> 6, pix = j & 63;
        xs[nd][ch][(pix >> 3) + 1][(pix & 7) + 1] =
            atom[(size_t)(nd ? n1 : n0) * 1024 + j];
    }
    __syncthreads();

    const int nd   = t >> 7;
    const int conv = (t >> 6) & 1;
    const int c    = (t >> 3) & 7;
    const int row  = t & 7;

    float tf[8] = {0,0,0,0,0,0,0,0};
    float tc[8] = {0,0,0,0,0,0,0,0};
    const float* zrow = &xs[nd][0][row][0];
    const float2* wbase = (const float2*)&ws[conv][0][0][c][0];

    #pragma unroll 4
    for (int cin = 0; cin < 16; ++cin) {
        float2 w[9];
        #pragma unroll
        for (int j = 0; j < 9; ++j) w[j] = wbase[(cin * 9 + j) * 8];
        float r[3][12];
        #pragma unroll
        for (int k = 0; k < 3; ++k) {
            const float4* rp = (const float4*)(zrow + cin * 120 + k * 12);
            float4 a = rp[0], b = rp[1], d = rp[2];
            r[k][0]=a.x; r[k][1]=a.y; r[k][2]=a.z; r[k][3]=a.w;
            r[k][4]=b.x; r[k][5]=b.y; r[k][6]=b.z; r[k][7]=b.w;
            r[k][8]=d.x; r[k][9]=d.y; r[k][10]=d.z; r[k][11]=d.w;
        }
        #pragma unroll
        for (int x = 0; x < 8; ++x) {
            float sf = tf[x], sc = tc[x];
            #pragma unroll
            for (int k = 0; k < 3; ++k) {
                sf += w[k*3+0].x * r[k][x] + w[k*3+1].x * r[k][x+1] + w[k*3+2].x * r[k][x+2];
                sc += w[k*3+0].y * r[k][x] + w[k*3+1].y * r[k][x+1] + w[k*3+2].y * r[k][x+2];
            }
            tf[x] = sf; tc[x] = sc;
        }
    }
    if (nd == 1 && dup) return;
    const size_t base = (size_t)(nd ? n1 : n0) * 1024;
    float* dst = conv ? nc : zc;
    #pragma unroll
    for (int x = 0; x < 8; ++x) {
        dst[base + c * 64 + row * 8 + x]       = tf[x];
        dst[base + (c + 8) * 64 + row * 8 + x] = tc[x];
    }
}

// ---------------------------------------------------------------------------
// Kernel B: node-major edge processing. One block per node n.
// Two 128-thread halves each process alternate edges of n's bucket:
//   z = elu(nc[n]*zc[tgt]); t = conv3x3(z, lin_w)+b;
//   msg = sigmoid(t[:16])*softplus(t[16:]); macc += msg  (registers)
// Then cross-half combine + fused BN/softplus epilogue, single write. No atomics.
// ---------------------------------------------------------------------------
__global__ __launch_bounds__(256, 4) void node_edge_kernel(
    const float* __restrict__ atom, const float* __restrict__ zc,
    const float* __restrict__ nc, const int* __restrict__ offsets,
    const int* __restrict__ bucket_tgt, const float* __restrict__ wst_lin,
    const float* __restrict__ lin_b, const float* __restrict__ gamma,
    const float* __restrict__ beta, float* __restrict__ out)
{
    __shared__ float zs[2][16][10][12];      // 15360 B (also reused for combine)
    __shared__ float ws[16][9][16][2];       // 18432 B [cin][j][c][h]
    __shared__ float bs[32];
    const int n = blockIdx.x;
    const int t = threadIdx.x;
    const int nd = t >> 7;                   // half id
    const int th = t & 127;

    float* wsf = &ws[0][0][0][0];
    for (int i = t; i < 4608; i += 256) wsf[i] = wst_lin[i];
    if (t < 32) bs[t] = lin_b[t];
    float* zsf = &zs[0][0][0][0];
    for (int i = t; i < 2 * 16 * 10 * 12; i += 256) zsf[i] = 0.f;   // zero incl. pad

    const int off = offsets[n];
    const int deg = offsets[n + 1] - off;

    // nc[n] fragment for this thread's staging slots (fixed mapping j = th + 128k)
    float nc8[8];
    #pragma unroll
    for (int k = 0; k < 8; ++k) nc8[k] = nc[(size_t)n * 1024 + th + 128 * k];

    const int c   = (t >> 3) & 15;
    const int row = t & 7;
    const float* zrow = &zs[nd][0][row][0];
    const float2* wbase = (const float2*)&ws[0][0][c][0];

    __syncthreads();
    const float bf = bs[c], bc = bs[c + 16];

    float macc[8] = {0,0,0,0,0,0,0,0};
    const int iters = (deg + 1) >> 1;
    for (int it = 0; it < iters; ++it) {
        const int je = 2 * it + nd;
        const bool valid = je < deg;
        if (valid) {
            const int tgt = bucket_tgt[off + je];
            const float* zp = zc + (size_t)tgt * 1024;
            #pragma unroll
            for (int k = 0; k < 8; ++k) {
                int j = th + 128 * k;
                float z = nc8[k] * zp[j];
                z = (z > 0.f) ? z : expm1f(z);   // elu
                int ch = j >> 6, y = (j >> 3) & 7, x = j & 7;
                zs[nd][ch][y + 1][x + 1] = z;
            }
        }
        __syncthreads();
        if (valid) {
            float tf[8] = {0,0,0,0,0,0,0,0};
            float tc[8] = {0,0,0,0,0,0,0,0};
            #pragma unroll 4
            for (int cin = 0; cin < 16; ++cin) {
                float2 w[9];
                #pragma unroll
                for (int j = 0; j < 9; ++j) w[j] = wbase[(cin * 9 + j) * 16];
                float r[3][12];
                #pragma unroll
                for (int k = 0; k < 3; ++k) {
                    const float4* rp = (const float4*)(zrow + cin * 120 + k * 12);
                    float4 a = rp[0], b = rp[1], d = rp[2];
                    r[k][0]=a.x; r[k][1]=a.y; r[k][2]=a.z; r[k][3]=a.w;
                    r[k][4]=b.x; r[k][5]=b.y; r[k][6]=b.z; r[k][7]=b.w;
                    r[k][8]=d.x; r[k][9]=d.y; r[k][10]=d.z; r[k][11]=d.w;
                }
                #pragma unroll
                for (int x = 0; x < 8; ++x) {
                    float sf = tf[x], sc = tc[x];
                    #pragma unroll
                    for (int k = 0; k < 3; ++k) {
                        sf += w[k*3+0].x * r[k][x] + w[k*3+1].x * r[k][x+1] + w[k*3+2].x * r[k][x+2];
                        sc += w[k*3+0].y * r[k][x] + w[k*3+1].y * r[k][x+1] + w[k*3+2].y * r[k][x+2];
                    }
                    tf[x] = sf; tc[x] = sc;
                }
            }
            #pragma unroll
            for (int x = 0; x < 8; ++x) {
                float f = tf[x] + bf;
                float co = tc[x] + bc;
                float sig = 1.f / (1.f + expf(-f));
                macc[x] += sig * softplusf(co);
            }
        }
        __syncthreads();
    }

    // cross-half combine through (now-free) zs, +1-padded to dodge conflicts
    float* comb = &zs[0][0][0][0];
    if (nd == 1) {
        #pragma unroll
        for (int x = 0; x < 8; ++x) comb[c * 65 + row * 8 + x] = macc[x];
    }
    __syncthreads();
    if (nd == 0) {
        const size_t base = (size_t)n * 1024 + c * 64 + row * 8;
        const float scale = gamma[c] * (1.f / sqrtf(1.f + 1e-5f));
        const float bet = beta[c];
        #pragma unroll
        for (int x = 0; x < 8; ++x) {
            float m = macc[x] + comb[c * 65 + row * 8 + x];
            float a = atom[base + x];
            out[base + x] = softplusf(a + (a + m) * scale + bet);
        }
    }
}

extern "C" void kernel_launch(void* const* d_in, const int* in_sizes, int n_in,
                              void* d_out, int out_size, void* d_ws, size_t ws_size,
                              hipStream_t stream) {
    const float* atom   = (const float*)d_in[0];
    const int*   esrc   = (const int*)d_in[1];
    const int*   etgt   = (const int*)d_in[2];
    const float* edge_w = (const float*)d_in[3];
    const float* node_w = (const float*)d_in[4];
    const float* lin_w  = (const float*)d_in[5];
    const float* lin_b  = (const float*)d_in[6];
    const float* gamma  = (const float*)d_in[7];
    const float* beta   = (const float*)d_in[8];
    float* out = (float*)d_out;

    const int total = in_sizes[0];      // N*16*8*8
    const int N = total / 1024;         // 8000
    const int E = in_sizes[1];          // 48000

    char* wsb = (char*)d_ws;
    float* zcb      = (float*)wsb;                                  // total fp32
    float* ncb      = (float*)(wsb + (size_t)total * 4);            // total fp32
    float* wst_lin  = (float*)(wsb + (size_t)total * 8);            // 4608
    float* wst_node = wst_lin + 4608;                               // 4608
    int*   counts   = (int*)(wst_node + 4608);                      // N
    int*   cursor   = counts + N;                                   // N
    int*   offsets  = cursor + N;                                   // N+1
    int*   bucket   = offsets + N + 1;                              // E

    hipMemsetAsync(counts, 0, (size_t)2 * N * 4, stream);           // counts+cursor
    prep_kernel<<<1, 256, 0, stream>>>(edge_w, node_w, lin_w, wst_lin, wst_node);
    hist_kernel<<<(E + 255) / 256, 256, 0, stream>>>(esrc, counts, E);
    scan_kernel<<<1, 256, 0, stream>>>(counts, offsets, N);
    scatter_kernel<<<(E + 255) / 256, 256, 0, stream>>>(esrc, etgt, offsets, cursor, bucket, E);
    node_conv_kernel<<<(N + 1) / 2, 256, 0, stream>>>(atom, wst_node, zcb, ncb, N);
    node_edge_kernel<<<N, 256, 0, stream>>>(atom, zcb, ncb, offsets, bucket,
                                            wst_lin, lin_b, gamma, beta, out);
}

// Round 5
// 471.489 us; speedup vs baseline: 3.3072x; 1.7141x over previous
//
#include <hip/hip_runtime.h>

typedef __attribute__((ext_vector_type(8))) short short8;   // 8 bf16 = 4 VGPRs (MFMA A/B frag)
typedef __attribute__((ext_vector_type(4))) float floatx4;  // MFMA C/D frag

__device__ __forceinline__ float softplusf(float x) {
    return fmaxf(x, 0.f) + log1pf(expf(-fabsf(x)));
}
__device__ __forceinline__ unsigned short f2bf(float x) {   // fp32 -> bf16 RNE (finite)
    unsigned u = __float_as_uint(x);
    u += 0x7fff + ((u >> 16) & 1);
    return (unsigned short)(u >> 16);
}
__device__ __forceinline__ float bf2f(unsigned short h) {
    return __uint_as_float(((unsigned)h) << 16);
}

// ---------------------------------------------------------------------------
// Kernel P: weight prep.
// 1) wst_node (node_conv staging layout, as before)
// 2) wfrag: lin_w as bf16 hi/lo MFMA B-fragments in exact lane order:
//    wfrag[((ver*2+nt)*5+s)*512 + lane*8 + j]; k=q*8+j -> tap=2s+(q>>1), cin=(q&1)*8+j
//    cout = nt*16 + (lane&15); tap 9 (pad) -> 0.
// ---------------------------------------------------------------------------
__global__ __launch_bounds__(256) void prep_kernel(
    const float* __restrict__ edge_w, const float* __restrict__ node_w,
    const float* __restrict__ lin_w,
    float* __restrict__ wst_node, short* __restrict__ wfrag)
{
    const int t = threadIdx.x;
    for (int i = t; i < 4608; i += 256) {
        int h = i & 1;
        int c = (i >> 1) & 7;
        int r = i >> 4;                    // conv*144 + cin*9 + j
        int conv = r / 144;
        int r2 = r - conv * 144;
        wst_node[i] = (conv == 0 ? edge_w : node_w)[(c + 8 * h) * 144 + r2];
    }
    for (int i = t; i < 10240; i += 256) {
        int idx = i;
        int j = idx & 7; idx >>= 3;
        int lane = idx & 63; idx >>= 6;
        int s = idx % 5; idx /= 5;
        int nt = idx & 1;
        int ver = idx >> 1;
        int c = lane & 15, q = lane >> 4;
        int tap = 2 * s + (q >> 1);
        int cin = (q & 1) * 8 + j;
        int cout = nt * 16 + c;
        float v = (tap < 9) ? lin_w[cout * 144 + cin * 9 + tap] : 0.f;
        unsigned short hi = f2bf(v);
        wfrag[i] = (short)(ver ? f2bf(v - bf2f(hi)) : hi);
    }
}

// ---------------------------------------------------------------------------
// Binning: histogram -> exclusive scan -> scatter
// ---------------------------------------------------------------------------
__global__ __launch_bounds__(256) void hist_kernel(
    const int* __restrict__ esrc, int* __restrict__ counts, int E)
{
    int i = blockIdx.x * 256 + threadIdx.x;
    if (i < E) atomicAdd(&counts[esrc[i]], 1);
}

__global__ __launch_bounds__(256) void scan_kernel(
    const int* __restrict__ counts, int* __restrict__ offsets, int N)
{
    __shared__ int part[256];
    const int t = threadIdx.x;
    const int chunk = (N + 255) / 256;
    const int base = t * chunk;
    int s = 0;
    for (int i = 0; i < chunk; ++i) {
        int idx = base + i;
        if (idx < N) s += counts[idx];
    }
    part[t] = s;
    __syncthreads();
    for (int d = 1; d < 256; d <<= 1) {
        int v = (t >= d) ? part[t - d] : 0;
        __syncthreads();
        part[t] += v;
        __syncthreads();
    }
    int excl = (t == 0) ? 0 : part[t - 1];
    for (int i = 0; i < chunk; ++i) {
        int idx = base + i;
        if (idx < N) { offsets[idx] = excl; excl += counts[idx]; }
    }
    if (t == 255) offsets[N] = excl;
}

__global__ __launch_bounds__(256) void scatter_kernel(
    const int* __restrict__ esrc, const int* __restrict__ etgt,
    const int* __restrict__ offsets, int* __restrict__ cursor,
    int* __restrict__ bucket_tgt, int E)
{
    int i = blockIdx.x * 256 + threadIdx.x;
    if (i < E) {
        int s = esrc[i];
        int pos = atomicAdd(&cursor[s], 1);
        bucket_tgt[offsets[s] + pos] = etgt[i];
    }
}

// ---------------------------------------------------------------------------
// Kernel A: node convs (fp32 VALU, unchanged from R4 — not the bottleneck yet)
// ---------------------------------------------------------------------------
__global__ __launch_bounds__(256, 4) void node_conv_kernel(
    const float* __restrict__ atom, const float* __restrict__ wst_node,
    float* __restrict__ zc, float* __restrict__ nc, int N)
{
    __shared__ float xs[2][16][10][12];
    __shared__ float ws[2][16][9][8][2];
    const int t = threadIdx.x;
    const int n0 = blockIdx.x * 2;
    const bool dup = (n0 + 1 >= N);
    const int n1 = dup ? n0 : n0 + 1;

    float* wsf = &ws[0][0][0][0][0];
    for (int i = t; i < 4608; i += 256) wsf[i] = wst_node[i];
    float* xsf = &xs[0][0][0][0];
    for (int i = t; i < 2 * 16 * 10 * 12; i += 256) xsf[i] = 0.f;
    __syncthreads();
    for (int i = t; i < 2048; i += 256) {
        int nd = i >> 10, j = i & 1023;
        int ch = j >> 6, pix = j & 63;
        xs[nd][ch][(pix >> 3) + 1][(pix & 7) + 1] =
            atom[(size_t)(nd ? n1 : n0) * 1024 + j];
    }
    __syncthreads();

    const int nd   = t >> 7;
    const int conv = (t >> 6) & 1;
    const int c    = (t >> 3) & 7;
    const int row  = t & 7;

    float tf[8] = {0,0,0,0,0,0,0,0};
    float tc[8] = {0,0,0,0,0,0,0,0};
    const float* zrow = &xs[nd][0][row][0];
    const float2* wbase = (const float2*)&ws[conv][0][0][c][0];

    #pragma unroll 4
    for (int cin = 0; cin < 16; ++cin) {
        float2 w[9];
        #pragma unroll
        for (int j = 0; j < 9; ++j) w[j] = wbase[(cin * 9 + j) * 8];
        float r[3][12];
        #pragma unroll
        for (int k = 0; k < 3; ++k) {
            const float4* rp = (const float4*)(zrow + cin * 120 + k * 12);
            float4 a = rp[0], b = rp[1], d = rp[2];
            r[k][0]=a.x; r[k][1]=a.y; r[k][2]=a.z; r[k][3]=a.w;
            r[k][4]=b.x; r[k][5]=b.y; r[k][6]=b.z; r[k][7]=b.w;
            r[k][8]=d.x; r[k][9]=d.y; r[k][10]=d.z; r[k][11]=d.w;
        }
        #pragma unroll
        for (int x = 0; x < 8; ++x) {
            float sf = tf[x], sc = tc[x];
            #pragma unroll
            for (int k = 0; k < 3; ++k) {
                sf += w[k*3+0].x * r[k][x] + w[k*3+1].x * r[k][x+1] + w[k*3+2].x * r[k][x+2];
                sc += w[k*3+0].y * r[k][x] + w[k*3+1].y * r[k][x+1] + w[k*3+2].y * r[k][x+2];
            }
            tf[x] = sf; tc[x] = sc;
        }
    }
    if (nd == 1 && dup) return;
    const size_t base = (size_t)(nd ? n1 : n0) * 1024;
    float* dst = conv ? nc : zc;
    #pragma unroll
    for (int x = 0; x < 8; ++x) {
        dst[base + c * 64 + row * 8 + x]       = tf[x];
        dst[base + (c + 8) * 64 + row * 8 + x] = tc[x];
    }
}

// ---------------------------------------------------------------------------
// Kernel B: node-major edge processing via MFMA (bf16 hi/lo x3 split).
// One block per node; 4 waves = 4 M-tiles of 16 pixels; N = 32 couts (2 tiles).
// K = cin(16) x taps(9) padded to 160 -> 5 MFMA K-steps of 32.
// Per edge: stage z=elu(nc*zc) into LDS as packed bf16 hi/lo (cin-fastest,
// 12-dword pixel pitch -> every A-frag = one aligned ds_read_b128), then
// 30 MFMA, then sigmoid*softplus accumulated in registers. No atomics.
// ---------------------------------------------------------------------------
__global__ __launch_bounds__(256, 3) void node_edge_kernel(
    const float* __restrict__ atom, const float* __restrict__ zc,
    const float* __restrict__ nc, const int* __restrict__ offsets,
    const int* __restrict__ bucket_tgt, const short* __restrict__ wfrag,
    const float* __restrict__ lin_b, const float* __restrict__ gamma,
    const float* __restrict__ beta, float* __restrict__ out)
{
    __shared__ unsigned zbuf[2][1336];     // [hi/lo][pixel(10x10)*12 + cinpair], 10.7 KB
    const int n = blockIdx.x;
    const int t = threadIdx.x;
    const int lane = t & 63;
    const int wv = t >> 6;                 // wave id = M-tile
    const int c = lane & 15;               // cout (N) / m (M) index
    const int q = lane >> 4;               // quad

    // zero LDS once (borders + tap-9 overflow region must read as 0.0)
    for (int i = t; i < 2 * 1336; i += 256) (&zbuf[0][0])[i] = 0u;

    // W fragments -> registers (prearranged lane order, L2-hot)
    const short8* wf = (const short8*)wfrag;
    short8 W[2][2][5];                     // [ver hi/lo][ntile][step]
    #pragma unroll
    for (int v = 0; v < 2; ++v)
        #pragma unroll
        for (int nt = 0; nt < 2; ++nt)
            #pragma unroll
            for (int s = 0; s < 5; ++s)
                W[v][nt][s] = wf[(((v * 2) + nt) * 5 + s) * 64 + lane];

    // A-frag LDS dword bases per K-step (lane-fixed)
    const int m15 = lane & 15;
    const int apy = wv * 2 + (m15 >> 3);   // pixel row (0..7)
    const int apx = m15 & 7;
    int abase[5];
    #pragma unroll
    for (int s = 0; s < 5; ++s) {
        int tap = 2 * s + (q >> 1);        // 0..9 (9 = zero pad, zero-W)
        int ky = tap / 3, kx = tap - 3 * ky;
        abase[s] = ((apy + ky) * 10 + (apx + kx)) * 12 + (q & 1) * 4;
    }

    // staging mapping: thread t handles cinpairs cp, cp+4 at pixel p
    const int cp = t >> 6;
    const int p = t & 63;
    const int i0 = cp * 128 + p;
    const int pix12 = (((p >> 3) + 1) * 10 + (p & 7) + 1) * 12;
    const size_t nb = (size_t)n * 1024;
    const float nv0 = nc[nb + i0], nv1 = nc[nb + i0 + 64];
    const float nv2 = nc[nb + i0 + 512], nv3 = nc[nb + i0 + 576];
    const float bfv = lin_b[c], bcv = lin_b[c + 16];

    const int off = offsets[n];
    const int deg = offsets[n + 1] - off;

    float macc[4] = {0.f, 0.f, 0.f, 0.f};
    float z0, z1, z2, z3;
    if (deg > 0) {                          // prefetch edge 0
        const float* zp = zc + (size_t)bucket_tgt[off] * 1024;
        z0 = zp[i0]; z1 = zp[i0 + 64]; z2 = zp[i0 + 512]; z3 = zp[i0 + 576];
    }
    __syncthreads();                        // zbuf zeroing complete

    for (int it = 0; it < deg; ++it) {
        // stage: elu + bf16 hi/lo split + packed LDS write
        float a0 = nv0 * z0; a0 = (a0 > 0.f) ? a0 : expm1f(a0);
        float a1 = nv1 * z1; a1 = (a1 > 0.f) ? a1 : expm1f(a1);
        float a2 = nv2 * z2; a2 = (a2 > 0.f) ? a2 : expm1f(a2);
        float a3 = nv3 * z3; a3 = (a3 > 0.f) ? a3 : expm1f(a3);
        unsigned short h0 = f2bf(a0), h1 = f2bf(a1), h2 = f2bf(a2), h3 = f2bf(a3);
        unsigned short l0 = f2bf(a0 - bf2f(h0)), l1 = f2bf(a1 - bf2f(h1));
        unsigned short l2 = f2bf(a2 - bf2f(h2)), l3 = f2bf(a3 - bf2f(h3));
        zbuf[0][pix12 + cp]     = (unsigned)h0 | ((unsigned)h1 << 16);
        zbuf[1][pix12 + cp]     = (unsigned)l0 | ((unsigned)l1 << 16);
        zbuf[0][pix12 + cp + 4] = (unsigned)h2 | ((unsigned)h3 << 16);
        zbuf[1][pix12 + cp + 4] = (unsigned)l2 | ((unsigned)l3 << 16);
        __syncthreads();

        if (it + 1 < deg) {                 // prefetch next edge (latency hidden by MFMA)
            const float* zp = zc + (size_t)bucket_tgt[off + it + 1] * 1024;
            z0 = zp[i0]; z1 = zp[i0 + 64]; z2 = zp[i0 + 512]; z3 = zp[i0 + 576];
        }

        floatx4 acc0 = {0.f, 0.f, 0.f, 0.f}, acc1 = {0.f, 0.f, 0.f, 0.f};
        #pragma unroll
        for (int s = 0; s < 5; ++s) {
            short8 Ah = *(const short8*)&zbuf[0][abase[s]];
            short8 Al = *(const short8*)&zbuf[1][abase[s]];
            acc0 = __builtin_amdgcn_mfma_f32_16x16x32_bf16(Ah, W[0][0][s], acc0, 0, 0, 0);
            acc1 = __builtin_amdgcn_mfma_f32_16x16x32_bf16(Ah, W[0][1][s], acc1, 0, 0, 0);
            acc0 = __builtin_amdgcn_mfma_f32_16x16x32_bf16(Al, W[0][0][s], acc0, 0, 0, 0);
            acc1 = __builtin_amdgcn_mfma_f32_16x16x32_bf16(Al, W[0][1][s], acc1, 0, 0, 0);
            acc0 = __builtin_amdgcn_mfma_f32_16x16x32_bf16(Ah, W[1][0][s], acc0, 0, 0, 0);
            acc1 = __builtin_amdgcn_mfma_f32_16x16x32_bf16(Ah, W[1][1][s], acc1, 0, 0, 0);
        }
        // epilogue: t_f = acc0 (couts 0..15), t_c = acc1 (couts 16..31), same lane/reg
        #pragma unroll
        for (int r = 0; r < 4; ++r) {
            float f = acc0[r] + bfv;
            float co = acc1[r] + bcv;
            macc[r] += (1.f / (1.f + expf(-f))) * softplusf(co);
        }
        __syncthreads();                    // before next staging overwrite
    }

    // fused BN + softplus, single write; pixel = wv*16 + q*4 + r, cout = c
    const size_t obase = (size_t)n * 1024 + (size_t)c * 64 + wv * 16 + q * 4;
    const float4 av = *(const float4*)&atom[obase];
    const float scale = gamma[c] * (1.f / sqrtf(1.f + 1e-5f));
    const float bet = beta[c];
    float4 ov;
    ov.x = softplusf(av.x + (av.x + macc[0]) * scale + bet);
    ov.y = softplusf(av.y + (av.y + macc[1]) * scale + bet);
    ov.z = softplusf(av.z + (av.z + macc[2]) * scale + bet);
    ov.w = softplusf(av.w + (av.w + macc[3]) * scale + bet);
    *(float4*)&out[obase] = ov;
}

extern "C" void kernel_launch(void* const* d_in, const int* in_sizes, int n_in,
                              void* d_out, int out_size, void* d_ws, size_t ws_size,
                              hipStream_t stream) {
    const float* atom   = (const float*)d_in[0];
    const int*   esrc   = (const int*)d_in[1];
    const int*   etgt   = (const int*)d_in[2];
    const float* edge_w = (const float*)d_in[3];
    const float* node_w = (const float*)d_in[4];
    const float* lin_w  = (const float*)d_in[5];
    const float* lin_b  = (const float*)d_in[6];
    const float* gamma  = (const float*)d_in[7];
    const float* beta   = (const float*)d_in[8];
    float* out = (float*)d_out;

    const int total = in_sizes[0];      // N*16*8*8
    const int N = total / 1024;         // 8000
    const int E = in_sizes[1];          // 48000

    char* wsb = (char*)d_ws;
    float* zcb      = (float*)wsb;                                  // total fp32
    float* ncb      = (float*)(wsb + (size_t)total * 4);            // total fp32
    float* wst_node = (float*)(wsb + (size_t)total * 8);            // 4608 fp32
    short* wfrag    = (short*)(wsb + (size_t)total * 8 + 4608 * 4); // 10240 bf16 (16B-aligned)
    int*   counts   = (int*)(wfrag + 10240);                        // N
    int*   cursor   = counts + N;                                   // N
    int*   offsets  = cursor + N;                                   // N+1
    int*   bucket   = offsets + N + 1;                              // E

    hipMemsetAsync(counts, 0, (size_t)2 * N * 4, stream);           // counts+cursor
    prep_kernel<<<1, 256, 0, stream>>>(edge_w, node_w, lin_w, wst_node, wfrag);
    hist_kernel<<<(E + 255) / 256, 256, 0, stream>>>(esrc, counts, E);
    scan_kernel<<<1, 256, 0, stream>>>(counts, offsets, N);
    scatter_kernel<<<(E + 255) / 256, 256, 0, stream>>>(esrc, etgt, offsets, cursor, bucket, E);
    node_conv_kernel<<<(N + 1) / 2, 256, 0, stream>>>(atom, wst_node, zcb, ncb, N);
    node_edge_kernel<<<N, 256, 0, stream>>>(atom, zcb, ncb, offsets, bucket,
                                            wfrag, lin_b, gamma, beta, out);
}

// Round 6
// 295.445 us; speedup vs baseline: 5.2779x; 1.5959x over previous
//
#include <hip/hip_runtime.h>

typedef __attribute__((ext_vector_type(8))) short short8;   // 8 bf16 (MFMA A/B frag)
typedef __attribute__((ext_vector_type(4))) float floatx4;  // MFMA C/D frag

#define REGSZ 2640   // per-wave LDS region (dwords): hi[1320] + lo[1320]
#define LOOFF 1320

__device__ __forceinline__ float frcp(float x) { return __builtin_amdgcn_rcpf(x); }
__device__ __forceinline__ float fsigmoid(float x) { return frcp(1.f + __expf(-x)); }
__device__ __forceinline__ float fsoftplus(float x) {
    return fmaxf(x, 0.f) + __logf(1.f + __expf(-fabsf(x)));
}
__device__ __forceinline__ float felu(float x) { return x > 0.f ? x : __expf(x) - 1.f; }

// truncating fp32 -> (bf16 hi, bf16 lo) pair-pack: lo captures residual (err ~2^-17)
__device__ __forceinline__ void split2(float a0, float a1, unsigned& hi, unsigned& lo) {
    unsigned u0 = __float_as_uint(a0), u1 = __float_as_uint(a1);
    hi = (u0 >> 16) | (u1 & 0xffff0000u);
    float r0 = a0 - __uint_as_float(u0 & 0xffff0000u);
    float r1 = a1 - __uint_as_float(u1 & 0xffff0000u);
    lo = (__float_as_uint(r0) >> 16) | (__float_as_uint(r1) & 0xffff0000u);
}
__device__ __forceinline__ unsigned short f2bf_rne(float x) {
    unsigned u = __float_as_uint(x);
    u += 0x7fff + ((u >> 16) & 1);
    return (unsigned short)(u >> 16);
}
__device__ __forceinline__ float bf2f(unsigned short h) {
    return __uint_as_float(((unsigned)h) << 16);
}

// ---------------------------------------------------------------------------
// Kernel P: build MFMA B-fragments (bf16 hi/lo) for lin_w and for edge_w|node_w.
// layout: wfrag[((ver*2+nt)*5+s)*512 + lane*8 + j]; k=q*8+j -> tap=2s+(q>>1),
// cin=(q&1)*8+j; tap 9 (pad) -> 0.  lin: cout=nt*16+(lane&15).
// node: src = nt? node_w : edge_w; cout = lane&15.
// ---------------------------------------------------------------------------
__global__ __launch_bounds__(256) void prep_kernel(
    const float* __restrict__ edge_w, const float* __restrict__ node_w,
    const float* __restrict__ lin_w,
    short* __restrict__ wfrag_lin, short* __restrict__ wfrag_node)
{
    const int t = threadIdx.x;
    for (int i = t; i < 10240; i += 256) {
        int idx = i;
        int j = idx & 7; idx >>= 3;
        int lane = idx & 63; idx >>= 6;
        int s = idx % 5; idx /= 5;
        int nt = idx & 1;
        int ver = idx >> 1;
        int q = lane >> 4;
        int tap = 2 * s + (q >> 1);
        int cin = (q & 1) * 8 + j;
        // lin frag
        {
            int cout = nt * 16 + (lane & 15);
            float v = (tap < 9) ? lin_w[cout * 144 + cin * 9 + tap] : 0.f;
            unsigned short hi = f2bf_rne(v);
            wfrag_lin[i] = (short)(ver ? f2bf_rne(v - bf2f(hi)) : hi);
        }
        // node frag (nt0 = edge_w -> zc, nt1 = node_w -> nc)
        {
            int cout = lane & 15;
            const float* src = nt ? node_w : edge_w;
            float v = (tap < 9) ? src[cout * 144 + cin * 9 + tap] : 0.f;
            unsigned short hi = f2bf_rne(v);
            wfrag_node[i] = (short)(ver ? f2bf_rne(v - bf2f(hi)) : hi);
        }
    }
}

// ---------------------------------------------------------------------------
// Binning: histogram -> exclusive scan -> scatter
// ---------------------------------------------------------------------------
__global__ __launch_bounds__(256) void hist_kernel(
    const int* __restrict__ esrc, int* __restrict__ counts, int E)
{
    int i = blockIdx.x * 256 + threadIdx.x;
    if (i < E) atomicAdd(&counts[esrc[i]], 1);
}

__global__ __launch_bounds__(256) void scan_kernel(
    const int* __restrict__ counts, int* __restrict__ offsets, int N)
{
    __shared__ int part[256];
    const int t = threadIdx.x;
    const int chunk = (N + 255) / 256;
    const int base = t * chunk;
    int s = 0;
    for (int i = 0; i < chunk; ++i) {
        int idx = base + i;
        if (idx < N) s += counts[idx];
    }
    part[t] = s;
    __syncthreads();
    for (int d = 1; d < 256; d <<= 1) {
        int v = (t >= d) ? part[t - d] : 0;
        __syncthreads();
        part[t] += v;
        __syncthreads();
    }
    int excl = (t == 0) ? 0 : part[t - 1];
    for (int i = 0; i < chunk; ++i) {
        int idx = base + i;
        if (idx < N) { offsets[idx] = excl; excl += counts[idx]; }
    }
    if (t == 255) offsets[N] = excl;
}

__global__ __launch_bounds__(256) void scatter_kernel(
    const int* __restrict__ esrc, const int* __restrict__ etgt,
    const int* __restrict__ offsets, int* __restrict__ cursor,
    int* __restrict__ bucket_tgt, int E)
{
    int i = blockIdx.x * 256 + threadIdx.x;
    if (i < E) {
        int s = esrc[i];
        int pos = atomicAdd(&cursor[s], 1);
        bucket_tgt[offsets[s] + pos] = etgt[i];
    }
}

// ---------------------------------------------------------------------------
// Kernel A: node convs via MFMA, wave-private (1 wave = 1 node), no barriers.
// zc = conv3x3(atom, edge_w), nc = conv3x3(atom, node_w).
// ---------------------------------------------------------------------------
__global__ __launch_bounds__(256, 2) void node_conv_kernel(
    const float* __restrict__ atom, const short* __restrict__ wfrag_node,
    float* __restrict__ zc, float* __restrict__ nc, int N)
{
    __shared__ unsigned zbuf[4 * REGSZ];
    const int t = threadIdx.x;
    const int lane = t & 63;
    const int wv = t >> 6;
    const int n = blockIdx.x * 4 + wv;
    if (n >= N) return;                      // no barriers in this kernel
    unsigned* zb = &zbuf[wv * REGSZ];
    for (int i = lane; i < REGSZ; i += 64) zb[i] = 0u;

    const int c = lane & 15;                 // cout / A-row m
    const int q = lane >> 4;

    const short8* wf = (const short8*)wfrag_node;
    short8 W[2][2][5];
    #pragma unroll
    for (int v = 0; v < 2; ++v)
        #pragma unroll
        for (int nt = 0; nt < 2; ++nt)
            #pragma unroll
            for (int s = 0; s < 5; ++s)
                W[v][nt][s] = wf[(((v * 2) + nt) * 5 + s) * 64 + lane];

    int aoff[5];
    #pragma unroll
    for (int s = 0; s < 5; ++s) {
        int tap = 2 * s + (q >> 1);
        int ky = tap / 3, kx = tap - 3 * ky;
        aoff[s] = (((c >> 3) + ky) * 10 + (c & 7) + kx) * 12 + (q & 1) * 4;
    }

    // stage atom[n] (pixel = lane), hi/lo split
    const size_t nb = (size_t)n * 1024;
    float a[16];
    #pragma unroll
    for (int k = 0; k < 16; ++k) a[k] = atom[nb + k * 64 + lane];
    unsigned h[8], l[8];
    #pragma unroll
    for (int d = 0; d < 8; ++d) split2(a[2 * d], a[2 * d + 1], h[d], l[d]);
    const int sbase = (((lane >> 3) + 1) * 10 + (lane & 7) + 1) * 12;
    *(uint4*)&zb[sbase]     = make_uint4(h[0], h[1], h[2], h[3]);
    *(uint4*)&zb[sbase + 4] = make_uint4(h[4], h[5], h[6], h[7]);
    *(uint4*)&zb[LOOFF + sbase]     = make_uint4(l[0], l[1], l[2], l[3]);
    *(uint4*)&zb[LOOFF + sbase + 4] = make_uint4(l[4], l[5], l[6], l[7]);

    #pragma unroll
    for (int mt = 0; mt < 4; ++mt) {
        floatx4 ae = {0.f, 0.f, 0.f, 0.f}, an = {0.f, 0.f, 0.f, 0.f};
        const int mb = mt * 240;
        #pragma unroll
        for (int s = 0; s < 5; ++s) {
            short8 Ah = *(const short8*)&zb[mb + aoff[s]];
            short8 Al = *(const short8*)&zb[LOOFF + mb + aoff[s]];
            ae = __builtin_amdgcn_mfma_f32_16x16x32_bf16(Ah, W[0][0][s], ae, 0, 0, 0);
            an = __builtin_amdgcn_mfma_f32_16x16x32_bf16(Ah, W[0][1][s], an, 0, 0, 0);
            ae = __builtin_amdgcn_mfma_f32_16x16x32_bf16(Al, W[0][0][s], ae, 0, 0, 0);
            an = __builtin_amdgcn_mfma_f32_16x16x32_bf16(Al, W[0][1][s], an, 0, 0, 0);
            ae = __builtin_amdgcn_mfma_f32_16x16x32_bf16(Ah, W[1][0][s], ae, 0, 0, 0);
            an = __builtin_amdgcn_mfma_f32_16x16x32_bf16(Ah, W[1][1][s], an, 0, 0, 0);
        }
        // D: pixel = mt*16 + q*4 + r, cout = c
        *(floatx4*)&zc[nb + (size_t)c * 64 + mt * 16 + q * 4] = ae;
        *(floatx4*)&nc[nb + (size_t)c * 64 + mt * 16 + q * 4] = an;
    }
}

// ---------------------------------------------------------------------------
// Kernel B: node-major edge processing; wave-private edges (no loop barriers).
// Each wave handles edges off+wv, off+wv+4, ... of node n; stages
// z = elu(nc[n]*zc[tgt]) into its own LDS region (bf16 hi/lo), 120 MFMA,
// fast sigmoid*softplus into register macc. End: LDS reduce + fused BN/softplus.
// ---------------------------------------------------------------------------
__global__ __launch_bounds__(256, 2) void node_edge_kernel(
    const float* __restrict__ atom, const float* __restrict__ zc,
    const float* __restrict__ nc, const int* __restrict__ offsets,
    const int* __restrict__ bucket_tgt, const short* __restrict__ wfrag_lin,
    const float* __restrict__ lin_b, const float* __restrict__ gamma,
    const float* __restrict__ beta, float* __restrict__ out)
{
    __shared__ unsigned zbuf[4 * REGSZ];     // 42.2 KB; reused as reduce buffer
    const int n = blockIdx.x;
    const int t = threadIdx.x;
    const int lane = t & 63;
    const int wv = t >> 6;
    const int c = lane & 15;
    const int q = lane >> 4;
    unsigned* zb = &zbuf[wv * REGSZ];
    for (int i = lane; i < REGSZ; i += 64) zb[i] = 0u;

    const short8* wf = (const short8*)wfrag_lin;
    short8 W[2][2][5];
    #pragma unroll
    for (int v = 0; v < 2; ++v)
        #pragma unroll
        for (int nt = 0; nt < 2; ++nt)
            #pragma unroll
            for (int s = 0; s < 5; ++s)
                W[v][nt][s] = wf[(((v * 2) + nt) * 5 + s) * 64 + lane];

    int aoff[5];
    #pragma unroll
    for (int s = 0; s < 5; ++s) {
        int tap = 2 * s + (q >> 1);
        int ky = tap / 3, kx = tap - 3 * ky;
        aoff[s] = (((c >> 3) + ky) * 10 + (c & 7) + kx) * 12 + (q & 1) * 4;
    }

    const size_t nb = (size_t)n * 1024;
    float nv[16];
    #pragma unroll
    for (int k = 0; k < 16; ++k) nv[k] = nc[nb + k * 64 + lane];
    const int sbase = (((lane >> 3) + 1) * 10 + (lane & 7) + 1) * 12;

    const int off = offsets[n];
    const int deg = offsets[n + 1] - off;
    const int myE = (deg > wv) ? ((deg - wv + 3) >> 2) : 0;

    const float bf = lin_b[c], bc = lin_b[c + 16];
    float macc[4][4] = {{0.f}};

    float zv[16];
    if (myE > 0) {
        const float* zp = zc + (size_t)bucket_tgt[off + wv] * 1024;
        #pragma unroll
        for (int k = 0; k < 16; ++k) zv[k] = zp[k * 64 + lane];
    }

    for (int it = 0; it < myE; ++it) {
        float a[16];
        #pragma unroll
        for (int k = 0; k < 16; ++k) a[k] = felu(nv[k] * zv[k]);
        unsigned h[8], l[8];
        #pragma unroll
        for (int d = 0; d < 8; ++d) split2(a[2 * d], a[2 * d + 1], h[d], l[d]);
        *(uint4*)&zb[sbase]     = make_uint4(h[0], h[1], h[2], h[3]);
        *(uint4*)&zb[sbase + 4] = make_uint4(h[4], h[5], h[6], h[7]);
        *(uint4*)&zb[LOOFF + sbase]     = make_uint4(l[0], l[1], l[2], l[3]);
        *(uint4*)&zb[LOOFF + sbase + 4] = make_uint4(l[4], l[5], l[6], l[7]);

        if (it + 1 < myE) {                  // prefetch next edge during MFMA
            const float* zp = zc + (size_t)bucket_tgt[off + wv + 4 * (it + 1)] * 1024;
            #pragma unroll
            for (int k = 0; k < 16; ++k) zv[k] = zp[k * 64 + lane];
        }

        #pragma unroll
        for (int mt = 0; mt < 4; ++mt) {
            floatx4 a0 = {0.f, 0.f, 0.f, 0.f}, a1 = {0.f, 0.f, 0.f, 0.f};
            const int mb = mt * 240;
            #pragma unroll
            for (int s = 0; s < 5; ++s) {
                short8 Ah = *(const short8*)&zb[mb + aoff[s]];
                short8 Al = *(const short8*)&zb[LOOFF + mb + aoff[s]];
                a0 = __builtin_amdgcn_mfma_f32_16x16x32_bf16(Ah, W[0][0][s], a0, 0, 0, 0);
                a1 = __builtin_amdgcn_mfma_f32_16x16x32_bf16(Ah, W[0][1][s], a1, 0, 0, 0);
                a0 = __builtin_amdgcn_mfma_f32_16x16x32_bf16(Al, W[0][0][s], a0, 0, 0, 0);
                a1 = __builtin_amdgcn_mfma_f32_16x16x32_bf16(Al, W[0][1][s], a1, 0, 0, 0);
                a0 = __builtin_amdgcn_mfma_f32_16x16x32_bf16(Ah, W[1][0][s], a0, 0, 0, 0);
                a1 = __builtin_amdgcn_mfma_f32_16x16x32_bf16(Ah, W[1][1][s], a1, 0, 0, 0);
            }
            #pragma unroll
            for (int r = 0; r < 4; ++r)
                macc[mt][r] += fsigmoid(a0[r] + bf) * fsoftplus(a1[r] + bc);
        }
    }

    // cross-wave reduce through LDS (pad 65 -> 2-way max, free)
    __syncthreads();
    float* comb = (float*)zbuf;
    #pragma unroll
    for (int mt = 0; mt < 4; ++mt)
        #pragma unroll
        for (int r = 0; r < 4; ++r)
            comb[wv * 1040 + c * 65 + mt * 16 + q * 4 + r] = macc[mt][r];
    __syncthreads();

    {
        const int co = t >> 4;
        const int p0 = (t & 15) * 4;
        const float scale = gamma[co] * (1.f / sqrtf(1.f + 1e-5f));
        const float bet = beta[co];
        const float4 av = *(const float4*)&atom[nb + t * 4];
        float4 ov;
        float av4[4] = {av.x, av.y, av.z, av.w};
        float ov4[4];
        #pragma unroll
        for (int i = 0; i < 4; ++i) {
            float m = comb[co * 65 + p0 + i] + comb[1040 + co * 65 + p0 + i]
                    + comb[2080 + co * 65 + p0 + i] + comb[3120 + co * 65 + p0 + i];
            float aa = av4[i];
            ov4[i] = fsoftplus(aa + (aa + m) * scale + bet);
        }
        ov.x = ov4[0]; ov.y = ov4[1]; ov.z = ov4[2]; ov.w = ov4[3];
        *(float4*)&out[nb + t * 4] = ov;
    }
}

extern "C" void kernel_launch(void* const* d_in, const int* in_sizes, int n_in,
                              void* d_out, int out_size, void* d_ws, size_t ws_size,
                              hipStream_t stream) {
    const float* atom   = (const float*)d_in[0];
    const int*   esrc   = (const int*)d_in[1];
    const int*   etgt   = (const int*)d_in[2];
    const float* edge_w = (const float*)d_in[3];
    const float* node_w = (const float*)d_in[4];
    const float* lin_w  = (const float*)d_in[5];
    const float* lin_b  = (const float*)d_in[6];
    const float* gamma  = (const float*)d_in[7];
    const float* beta   = (const float*)d_in[8];
    float* out = (float*)d_out;

    const int total = in_sizes[0];      // N*16*8*8
    const int N = total / 1024;         // 8000
    const int E = in_sizes[1];          // 48000

    char* wsb = (char*)d_ws;
    float* zcb       = (float*)wsb;                                   // total fp32
    float* ncb       = (float*)(wsb + (size_t)total * 4);             // total fp32
    short* wfrag_lin = (short*)(wsb + (size_t)total * 8);             // 10240 (16B-aligned)
    short* wfrag_nod = wfrag_lin + 10240;                             // 10240
    int*   counts    = (int*)(wfrag_nod + 10240);                     // N
    int*   cursor    = counts + N;                                    // N
    int*   offsets   = cursor + N;                                    // N+1
    int*   bucket    = offsets + N + 1;                               // E

    hipMemsetAsync(counts, 0, (size_t)2 * N * 4, stream);             // counts+cursor
    prep_kernel<<<1, 256, 0, stream>>>(edge_w, node_w, lin_w, wfrag_lin, wfrag_nod);
    hist_kernel<<<(E + 255) / 256, 256, 0, stream>>>(esrc, counts, E);
    scan_kernel<<<1, 256, 0, stream>>>(counts, offsets, N);
    scatter_kernel<<<(E + 255) / 256, 256, 0, stream>>>(esrc, etgt, offsets, cursor, bucket, E);
    node_conv_kernel<<<(N + 3) / 4, 256, 0, stream>>>(atom, wfrag_nod, zcb, ncb, N);
    node_edge_kernel<<<N, 256, 0, stream>>>(atom, zcb, ncb, offsets, bucket,
                                            wfrag_lin, lin_b, gamma, beta, out);
}